// Round 18
// baseline (18054.311 us; speedup 1.0000x reference)
//
#include <hip/hip_runtime.h>

#define B_   128
#define IN_  128
#define D_   32
#define A_   8
#define C_   100000
#define P_   50

// ---- static device scratch ----
__device__ float  g_keys32[B_ * D_];   // f32 keys: L1 FMA, L2 FMA (41472 family)
__device__ float  g_qsqf[B_];          // seq mul+add sumsq
__device__ float  g_msq[A_ * C_];      // same
__device__ double g_q64[B_ * A_];

// TIES ON EQUAL f32 d2: HIGHER index first (np quicksort-argsort emulation probe)
__device__ __forceinline__ bool lexless(float d1, int i1, float d2, int i2) {
    return d1 < d2 || (d1 == d2 && i1 > i2);
}
__device__ __forceinline__ unsigned sortkey(float f) {
    unsigned u = __float_as_uint(f);
    return u ^ ((u >> 31) ? 0xFFFFFFFFu : 0x80000000u);
}

// sequential ascending mul+add sum of squares (separate roundings)
__device__ __forceinline__ float xla_seq_sumsq(const float* __restrict__ z) {
    float s = 0.0f;
#pragma unroll
    for (int i = 0; i < 32; ++i)
        s = __fadd_rn(s, __fmul_rn(z[i], z[i]));
    return s;
}

// ---------------- K1: MLP — both layers sequential-k FMA chains ----------------
__global__ void k_mlp(const float* __restrict__ x, const float* __restrict__ W1,
                      const float* __restrict__ b1, const float* __restrict__ W2,
                      const float* __restrict__ b2, float* __restrict__ out) {
    int b = blockIdx.x;
    int d = threadIdx.x;  // 32 threads
    __shared__ float h32[32];
    __shared__ float k32[32];

    float acc = 0.0f;
    for (int k = 0; k < IN_; ++k)
        acc = __fmaf_rn(x[b * IN_ + k], W1[k * D_ + d], acc);
    float hv = __fadd_rn(acc, b1[d]);
    h32[d] = hv > 0.0f ? hv : 0.0f;
    __syncthreads();

    float acc2 = 0.0f;
    for (int e = 0; e < D_; ++e)
        acc2 = __fmaf_rn(h32[e], W2[e * D_ + d], acc2);
    float kv = __fadd_rn(acc2, b2[d]);
    float kf = kv > 0.0f ? kv : 0.0f;

    k32[d] = kf;
    g_keys32[b * D_ + d] = kf;
    out[102656 + b * D_ + d] = kf;          // keys output (f32)
    __syncthreads();

    if (d == 0) g_qsqf[b] = xla_seq_sumsq(k32);
}

// ---------------- K1b: m_sq for all candidates, seq mul+add ----------------
__global__ __launch_bounds__(256) void k_msq(const float* __restrict__ dnd_keys) {
    int i = blockIdx.x * 256 + threadIdx.x;
    if (i < A_ * C_) {
        float z[32];
        const float* src = dnd_keys + (size_t)i * D_;
#pragma unroll
        for (int j = 0; j < 32; ++j) z[j] = src[j];
        g_msq[i] = xla_seq_sumsq(z);
    }
}

// ---------------- K2: brute-force top-50 per (b,a) ----------------
__global__ __launch_bounds__(128) void k_brute(const float* __restrict__ dnd_keys,
                                               const float* __restrict__ dnd_values,
                                               float* __restrict__ out) {
    const int p = blockIdx.x;
    const int b = p >> 3;
    const int a = p & 7;
    const int tid = threadIdx.x;

    __shared__ float kk[32];
    __shared__ float sd[128 * P_];
    __shared__ int   si[128 * P_];
    __shared__ float cd[256];
    __shared__ int   ci[256];
    __shared__ int   cnt_sh, scount;

    if (tid < 32) kk[tid] = g_keys32[b * D_ + tid];
    __syncthreads();
    const float qsq = g_qsqf[b];
    float k0[32];
#pragma unroll
    for (int j = 0; j < 32; ++j) k0[j] = kk[j];

    float td[P_];
    int   ti[P_];
    int   tn = 0;

    for (int c = tid; c < C_; c += 128) {
        const float* z = dnd_keys + ((size_t)a * C_ + (size_t)c) * D_;

        // cross: sequential ascending mul+add, no FMA (r16 config)
        float s = 0.0f;
#pragma unroll
        for (int m = 0; m < 32; ++m)
            s = __fadd_rn(s, __fmul_rn(z[m], k0[m]));

        float msq = g_msq[a * C_ + c];

        // d2 = (q_sq + m_sq) - 2.0*cross (2*cross exact)
        float d2 = __fsub_rn(__fadd_rn(qsq, msq), __fmul_rn(2.0f, s));

        if (tn < P_) {
            int j = tn++;
            while (j > 0 && lexless(d2, c, td[j - 1], ti[j - 1])) {
                td[j] = td[j - 1]; ti[j] = ti[j - 1]; --j;
            }
            td[j] = d2; ti[j] = c;
        } else if (lexless(d2, c, td[P_ - 1], ti[P_ - 1])) {
            int j = P_ - 1;
            while (j > 0 && lexless(d2, c, td[j - 1], ti[j - 1])) {
                td[j] = td[j - 1]; ti[j] = ti[j - 1]; --j;
            }
            td[j] = d2; ti[j] = c;
        }
    }

    for (int j = 0; j < P_; ++j) {
        sd[tid * P_ + j] = (j < tn) ? td[j] : __builtin_inff();
        si[tid * P_ + j] = (j < tn) ? ti[j] : -1;
    }
    __syncthreads();

    // binary search smallest sortkey u with count(<= u) >= 50 over 6400 entries
    unsigned lo = 0, hi = 0xFFFFFFFFu;
    for (int it = 0; it < 32; ++it) {
        unsigned mid = lo + ((hi - lo) >> 1);
        if (tid == 0) cnt_sh = 0;
        __syncthreads();
        int c = 0;
        for (int i = tid; i < 128 * P_; i += 128)
            if (sortkey(sd[i]) <= mid) ++c;
        if (c) atomicAdd(&cnt_sh, c);
        __syncthreads();
        if (cnt_sh >= P_) hi = mid; else lo = mid + 1;
        __syncthreads();
    }

    if (tid == 0) scount = 0;
    __syncthreads();
    for (int i = tid; i < 128 * P_; i += 128) {
        if (sortkey(sd[i]) <= hi) {
            int pos = atomicAdd(&scount, 1);
            if (pos < 256) { cd[pos] = sd[i]; ci[pos] = si[i]; }
        }
    }
    __syncthreads();
    for (int i = tid; i < 256; i += 128)
        if (i >= scount) { cd[i] = __builtin_inff(); ci[i] = -1; }
    __syncthreads();

    // bitonic-256 lex sort ascending (d2 asc, idx DESC on ties)
    for (int ksz = 2; ksz <= 256; ksz <<= 1) {
        for (int j = ksz >> 1; j > 0; j >>= 1) {
            for (int e = tid; e < 256; e += 128) {
                int ixj = e ^ j;
                if (ixj > e) {
                    bool up = ((e & ksz) == 0);
                    float a1 = cd[e], a2v = cd[ixj];
                    int   i1 = ci[e], i2 = ci[ixj];
                    bool sw = up ? lexless(a2v, i2, a1, i1) : lexless(a1, i1, a2v, i2);
                    if (sw) { cd[e] = a2v; cd[ixj] = a1; ci[e] = i2; ci[ixj] = i1; }
                }
            }
            __syncthreads();
        }
    }

    if (tid < P_) {
        float d2 = cd[tid];
        float sc = 1.0f / (fmaxf(d2, 0.0f) + 0.001f);
        out[256   + p * P_ + tid] = (float)ci[tid];   // indexes (f32)
        out[51456 + p * P_ + tid] = sc;               // scores  (f32)
    }
    __syncthreads();
    if (tid == 0) {
        double ssum = 0.0, qq = 0.0;
        for (int i = 0; i < P_; ++i) {
            double d2 = (double)fmaxf(cd[i], 0.0f);
            ssum += 1.0 / (d2 + 0.001);
        }
        for (int i = 0; i < P_; ++i) {
            double d2 = (double)fmaxf(cd[i], 0.0f);
            double sc = 1.0 / (d2 + 0.001);
            qq += (sc / ssum) * (double)dnd_values[(size_t)a * C_ + ci[i]];
        }
        g_q64[p] = qq;
    }
}

// ---------------- K3: values / actions ----------------
__global__ void k_final(float* __restrict__ out) {
    int b = threadIdx.x + blockIdx.x * 64;
    if (b < B_) {
        double best = -__builtin_inf();
        int ba = 0;
        for (int a = 0; a < A_; ++a) {
            double v = g_q64[b * A_ + a];
            if (v > best) { best = v; ba = a; }
        }
        out[b]       = (float)best;
        out[128 + b] = (float)ba;
    }
}

extern "C" void kernel_launch(void* const* d_in, const int* in_sizes, int n_in,
                              void* d_out, int out_size, void* d_ws, size_t ws_size,
                              hipStream_t stream) {
    const float* x          = (const float*)d_in[0];
    const float* W1         = (const float*)d_in[1];
    const float* b1         = (const float*)d_in[2];
    const float* W2         = (const float*)d_in[3];
    const float* b2         = (const float*)d_in[4];
    const float* dnd_keys   = (const float*)d_in[5];
    const float* dnd_values = (const float*)d_in[6];
    float* out = (float*)d_out;

    k_mlp<<<B_, 32, 0, stream>>>(x, W1, b1, W2, b2, out);
    k_msq<<<(A_ * C_ + 255) / 256, 256, 0, stream>>>(dnd_keys);
    k_brute<<<B_ * A_, 128, 0, stream>>>(dnd_keys, dnd_values, out);
    k_final<<<2, 64, 0, stream>>>(out);
}